// Round 8
// baseline (1452.951 us; speedup 1.0000x reference)
//
#include <hip/hip_runtime.h>
#include <hip/hip_bf16.h>
#include <stdint.h>

#define N_NODES 100000
#define N_RELS  8
#define N_EDGES 150000
#define KCOLS   1152   // K = 8*128 relation cols + 128 self-loop cols
#define TOT_E   (N_RELS * N_EDGES)
#define MAXM    500000 // AggM slot capacity (expected ~354K multi segments)

typedef short bf16x8 __attribute__((ext_vector_type(8)));
typedef float f32x4  __attribute__((ext_vector_type(4)));

__device__ __forceinline__ unsigned short f2b(float f) {
    union { float f; unsigned u; } v; v.f = f;
    unsigned r = v.u + 0x7FFF + ((v.u >> 16) & 1);   // RNE
    return (unsigned short)(r >> 16);
}
__device__ __forceinline__ float b2f(unsigned short h) {
    union { unsigned u; float f; } v; v.u = ((unsigned)h) << 16;
    return v.f;
}

// async 16B global->LDS (direct, no VGPR round trip)
#define GLD_LDS16(gp, lp)                                                     \
    __builtin_amdgcn_global_load_lds(                                         \
        (const __attribute__((address_space(1))) unsigned int*)(gp),          \
        (__attribute__((address_space(3))) unsigned int*)(lp), 16, 0, 0)

// ---------------------------------------------------------------------------
// Merged: cast x f32->bf16 | build BT[n][k] | per-(dst,rel) degree histogram
// ---------------------------------------------------------------------------
__global__ void prep_all(const float* __restrict__ X, const float* __restrict__ W,
                         const float* __restrict__ Wself, const int* __restrict__ dst,
                         unsigned short* __restrict__ xb, unsigned short* __restrict__ BT,
                         int* __restrict__ cnt8) {
    int t = blockIdx.x * 256 + threadIdx.x;
    if (t < N_NODES * 16) {
        const float4* p = (const float4*)(X + (size_t)t * 8);
        float4 a = p[0], b = p[1];
        unsigned short o[8] = { f2b(a.x), f2b(a.y), f2b(a.z), f2b(a.w),
                                f2b(b.x), f2b(b.y), f2b(b.z), f2b(b.w) };
        *(int4*)(xb + (size_t)t * 8) = *(const int4*)o;
        return;
    }
    int flat = t - N_NODES * 16;
    if (flat < 128 * KCOLS) {
        int n = flat / KCOLS, k = flat - n * KCOLS;
        float v;
        if (k < 1024) {
            int r = k >> 7, kk = k & 127;
            v = W[(r << 14) + (kk << 7) + n];
        } else {
            v = Wself[((k - 1024) << 7) + n];
        }
        BT[flat] = f2b(v);
        return;
    }
    int rem = flat - 128 * KCOLS;
    if (rem >= TOT_E) return;
    int r = rem / N_EDGES;
    int e = rem - r * N_EDGES;
    atomicAdd(&cnt8[dst[r * N_EDGES + e] * 8 + r], 1);
}

// exact CSR allocation: per-dst contiguous block (relation-sorted inside)
__global__ void alloc_k(const int* __restrict__ cnt8, int* __restrict__ cur8,
                        int* __restrict__ dbase, int* __restrict__ cursor) {
    int d = blockIdx.x * 256 + threadIdx.x;
    int lane = threadIdx.x & 63;
    int c[8]; int tot = 0;
    if (d < N_NODES) {
        int4 a = *(const int4*)&cnt8[d * 8];
        int4 b = *(const int4*)&cnt8[d * 8 + 4];
        c[0] = a.x; c[1] = a.y; c[2] = a.z; c[3] = a.w;
        c[4] = b.x; c[5] = b.y; c[6] = b.z; c[7] = b.w;
        tot = c[0] + c[1] + c[2] + c[3] + c[4] + c[5] + c[6] + c[7];
    } else {
#pragma unroll
        for (int r = 0; r < 8; ++r) c[r] = 0;
    }
    int pre = tot;
#pragma unroll
    for (int off = 1; off < 64; off <<= 1) {
        int v = __shfl_up(pre, off);
        if (lane >= off) pre += v;
    }
    int base = 0;
    if (lane == 63) base = atomicAdd(cursor, pre);
    base = __shfl(base, 63);
    if (d < N_NODES) {
        int b0 = base + (pre - tot);
        dbase[d] = b0;
        int p = 0;
#pragma unroll
        for (int r = 0; r < 8; ++r) { cur8[d * 8 + r] = b0 + p; p += c[r]; }
    }
}

// scatter src ids into exact slots (relation-sorted per dst)
__global__ void edge_scatter(const int* __restrict__ src, const int* __restrict__ dst,
                             int* __restrict__ cur8, int* __restrict__ ebuf) {
    int e = blockIdx.x * 256 + threadIdx.x;
    int r = blockIdx.y;
    if (e >= N_EDGES) return;
    int s = src[r * N_EDGES + e];
    int d = dst[r * N_EDGES + e];
    int slot = atomicAdd(&cur8[d * 8 + r], 1);
    ebuf[slot] = s;
}

// ---------------------------------------------------------------------------
// One wave per dst. Per (dst,rel): deg==0 -> ptab=-1; deg==1 -> ptab=src
// (gemm gathers xb row directly); deg>=2 -> gather+mean into compact AggM
// slot, ptab = 0x40000000|slot. Only ~44% of segments are materialized.
// ---------------------------------------------------------------------------
__global__ __launch_bounds__(256, 8) void agg_r(
    const unsigned short* __restrict__ xb, const int* __restrict__ cnt8,
    const int* __restrict__ dbase, const int* __restrict__ ebuf,
    unsigned short* __restrict__ AggM, int* __restrict__ ptab,
    int* __restrict__ mcur) {
    int d = (blockIdx.x << 2) + (threadIdx.x >> 6);
    if (d >= N_NODES) return;
    int lane = threadIdx.x & 63;

    int c = (lane < 8) ? cnt8[d * 8 + lane] : 0;
    int base = dbase[d];

    // exclusive scan (segment starts) + total over the 8 relation lanes
    int pre = 0, tot = 0;
#pragma unroll
    for (int i = 0; i < 8; ++i) {
        int ci = __shfl(c, i);
        if (i < lane) pre += ci;
        tot += ci;
    }
    int tl = tot > 64 ? 64 : tot;

    int rec = (lane < tl) ? ebuf[base + lane] : 0;

    // slot allocation for multi (deg>=2) segments: one atomic per wave
    bool ismulti = (lane < 8) && (c >= 2);
    unsigned long long mmask = __ballot(ismulti);
    int mcount = __popcll(mmask);
    int mpref  = __popcll(mmask & ((1ull << lane) - 1ull));
    int mbase = 0;
    if (lane == 0 && mcount) mbase = atomicAdd(mcur, mcount);
    mbase = __shfl(mbase, 0);
    int slotv = mbase + mpref;
    if (slotv > MAXM - 1) slotv = MAXM - 1;   // safety clamp

    // single-edge src broadcast (lane's own segment start)
    int srcv = __shfl(rec, pre & 63);

    if (lane < 8) {
        int pv;
        if (c == 0)      pv = -1;
        else if (c == 1) pv = srcv;
        else             pv = 0x40000000 | slotv;
        ptab[d * 8 + lane] = pv;
    }

    const unsigned short* xcol = xb + (lane << 1);
    int sr = 0;
#pragma unroll 1
    for (int r = 0; r < 8; ++r) {
        int kraw = __shfl(c, r);
        if (kraw >= 2) {
            float inv = 1.0f / (float)kraw;
            int k = kraw;
            if (sr + k > tl) k = tl - sr;
            float ax = 0.f, ay = 0.f;
            int j = 0;
            for (; j + 1 < k; j += 2) {
                int rc0 = __shfl(rec, sr + j);
                int rc1 = __shfl(rec, sr + j + 1);
                unsigned p0 = *(const unsigned*)&xcol[(size_t)rc0 * 128];
                unsigned p1 = *(const unsigned*)&xcol[(size_t)rc1 * 128];
                ax += b2f((unsigned short)(p0 & 0xFFFF));
                ay += b2f((unsigned short)(p0 >> 16));
                ax += b2f((unsigned short)(p1 & 0xFFFF));
                ay += b2f((unsigned short)(p1 >> 16));
            }
            if (j < k) {
                int rc0 = __shfl(rec, sr + j);
                unsigned p0 = *(const unsigned*)&xcol[(size_t)rc0 * 128];
                ax += b2f((unsigned short)(p0 & 0xFFFF));
                ay += b2f((unsigned short)(p0 >> 16));
            }
            int slot = __shfl(slotv, r);
            unsigned pk = (unsigned)f2b(ax * inv) | ((unsigned)f2b(ay * inv) << 16);
            *(unsigned*)&AggM[(size_t)slot * 128 + (lane << 1)] = pk;
        }
        sr += kraw;
    }
}

// ---------------------------------------------------------------------------
// out[N,128] f32 = relu( [Agg | xb][N,1152] @ BT^T + bias ), A resolved via
// ptab indirection (AggM slot / xb row / zero page). Async 16B DMA staging
// with XOR chunk swizzle; LDS = 68 KB -> 2 blocks/CU.
// ---------------------------------------------------------------------------
__global__ __launch_bounds__(256, 2) void gemm_out4(
    const unsigned short* __restrict__ AggM, const unsigned short* __restrict__ xb,
    const unsigned short* __restrict__ BT, const int* __restrict__ ptab,
    const unsigned short* __restrict__ zp, const float* __restrict__ bias,
    float* __restrict__ out) {
    __shared__ unsigned short As[128 * 128];   // 32 KB, swizzled chunks
    __shared__ unsigned short Bs[128 * 128];   // 32 KB, swizzled chunks
    __shared__ int PT[128 * 8];                //  4 KB  ptab rows of this block
    int t = threadIdx.x;
    int rowBase = blockIdx.x * 128;
    int w = t >> 6, lane = t & 63;
    int wr = w >> 1, wc = w & 1;
    int ml = lane & 15, quad = lane >> 4;

    f32x4 acc[4][4];
#pragma unroll
    for (int i = 0; i < 4; ++i)
#pragma unroll
        for (int j = 0; j < 4; ++j)
            acc[i][j] = (f32x4){0.f, 0.f, 0.f, 0.f};

    // preload ptab rows: PT[row*8+r]; global addr = rowBase*8 + i (contiguous)
    {
        int rowMax8 = (N_NODES - 1) * 8;
#pragma unroll
        for (int it = 0; it < 4; ++it) {
            int i = t + it * 256;
            int gi = rowBase * 8 + i;
            if (gi > rowMax8 + 7) gi = rowMax8 + (i & 7);   // clamp to last row
            PT[i] = ptab[gi];
        }
    }

    // staging decode (constant across kc): chunk Lc=it*256+t; row=Lc>>4;
    // stored chunk c'=Lc&15; global chunk c = c' ^ (row&15)
    int rA[8], cA[8];
#pragma unroll
    for (int it = 0; it < 8; ++it) {
        int Lc = it * 256 + t;
        rA[it] = Lc >> 4;
        cA[it] = (Lc & 15) ^ (rA[it] & 15);
    }
    __syncthreads();   // PT ready

    for (int kc = 0; kc < 9; ++kc) {
        // A: resolve indirection, DMA to LDS
        if (kc < 8) {
#pragma unroll
            for (int it = 0; it < 8; ++it) {
                int r = rA[it], c = cA[it];
                int pv = PT[r * 8 + kc];
                const unsigned short* gp;
                if (pv < 0)                  gp = zp + c * 8;
                else if (pv & 0x40000000)    gp = AggM + (size_t)(pv & 0x3FFFFFFF) * 128 + c * 8;
                else                         gp = xb + (size_t)pv * 128 + c * 8;
                GLD_LDS16(gp, As + ((size_t)(it * 256 + t)) * 8);
            }
        } else {
#pragma unroll
            for (int it = 0; it < 8; ++it) {
                int r = rA[it], c = cA[it];
                int grow = rowBase + r;
                if (grow > N_NODES - 1) grow = N_NODES - 1;
                GLD_LDS16(xb + (size_t)grow * 128 + c * 8,
                          As + ((size_t)(it * 256 + t)) * 8);
            }
        }
        // B: L2 -> LDS
#pragma unroll
        for (int it = 0; it < 8; ++it) {
            int r = rA[it], c = cA[it];
            GLD_LDS16(BT + (size_t)r * KCOLS + (kc << 7) + c * 8,
                      Bs + ((size_t)(it * 256 + t)) * 8);
        }
        __syncthreads();

#pragma unroll
        for (int kb = 0; kb < 4; ++kb) {
            int cs = kb * 4 + quad;            // k-chunk index (16B granules)
            int sw = (cs ^ ml) << 3;           // swizzled chunk offset, shorts
            bf16x8 a[4], b[4];
#pragma unroll
            for (int j = 0; j < 4; ++j)
                b[j] = *(const bf16x8*)&Bs[(wc * 64 + j * 16 + ml) * 128 + sw];
#pragma unroll
            for (int i = 0; i < 4; ++i)
                a[i] = *(const bf16x8*)&As[(wr * 64 + i * 16 + ml) * 128 + sw];
#pragma unroll
            for (int i = 0; i < 4; ++i)
#pragma unroll
                for (int j = 0; j < 4; ++j)
                    acc[i][j] = __builtin_amdgcn_mfma_f32_16x16x32_bf16(a[i], b[j], acc[i][j], 0, 0, 0);
        }
        __syncthreads();
    }

    // epilogue: + bias, relu, f32 store
#pragma unroll
    for (int i = 0; i < 4; ++i) {
#pragma unroll
        for (int j = 0; j < 4; ++j) {
            int col = wc * 64 + j * 16 + ml;
            float bv = bias[col];
#pragma unroll
            for (int rr = 0; rr < 4; ++rr) {
                int row = rowBase + wr * 64 + i * 16 + quad * 4 + rr;
                if (row < N_NODES) {
                    float v = acc[i][j][rr] + bv;
                    out[(size_t)row * 128 + col] = fmaxf(v, 0.f);
                }
            }
        }
    }
}

// ---------------------------------------------------------------------------
extern "C" void kernel_launch(void* const* d_in, const int* in_sizes, int n_in,
                              void* d_out, int out_size, void* d_ws, size_t ws_size,
                              hipStream_t stream) {
    const float* x     = (const float*)d_in[0];
    const float* W     = (const float*)d_in[1];
    const float* Wself = (const float*)d_in[2];
    const float* bias  = (const float*)d_in[3];
    const int*   src   = (const int*)d_in[4];
    const int*   dst   = (const int*)d_in[5];
    float* out = (float*)d_out;

    char* ws = (char*)d_ws;
    size_t off = 0;
    unsigned short* AggM = (unsigned short*)(ws + off); off += (size_t)MAXM * 128 * 2;    // 128.0 MB
    unsigned short* xb   = (unsigned short*)(ws + off); off += (size_t)N_NODES * 128 * 2; //  25.6 MB
    unsigned short* BT   = (unsigned short*)(ws + off); off += (size_t)128 * KCOLS * 2;   //   0.3 MB
    int* cnt8  = (int*)(ws + off); off += (size_t)N_NODES * 8 * 4;                        //   3.2 MB
    int* cur8  = (int*)(ws + off); off += (size_t)N_NODES * 8 * 4;                        //   3.2 MB
    int* dbase = (int*)(ws + off); off += (size_t)N_NODES * 4;                            //   0.4 MB
    int* ebuf  = (int*)(ws + off); off += (size_t)TOT_E * 4;                              //   4.8 MB
    int* ptab  = (int*)(ws + off); off += (size_t)N_NODES * 8 * 4;                        //   3.2 MB
    unsigned short* zp = (unsigned short*)(ws + off); off += 256;                         // zero page
    int* cursors = (int*)(ws + off); off += 256;   // [0]=edge cursor, [1]=multi cursor
                                                   // total ~168.8 MB

    hipMemsetAsync(cnt8, 0, (size_t)N_NODES * 8 * 4, stream);
    hipMemsetAsync(zp, 0, 512, stream);            // zero page + cursors

    int prep_threads = N_NODES * 16 + 128 * KCOLS + TOT_E;
    prep_all<<<(prep_threads + 255) / 256, 256, 0, stream>>>(x, W, Wself, dst, xb, BT, cnt8);

    alloc_k<<<(N_NODES + 255) / 256, 256, 0, stream>>>(cnt8, cur8, dbase, &cursors[0]);

    dim3 eg((N_EDGES + 255) / 256, N_RELS);
    edge_scatter<<<eg, 256, 0, stream>>>(src, dst, cur8, ebuf);

    agg_r<<<(N_NODES + 3) / 4, 256, 0, stream>>>(xb, cnt8, dbase, ebuf, AggM, ptab, &cursors[1]);

    gemm_out4<<<(N_NODES + 127) / 128, 256, 0, stream>>>(AggM, xb, BT, ptab, zp, bias, out);
}